// Round 1
// baseline (673.406 us; speedup 1.0000x reference)
//
#include <hip/hip_runtime.h>
#include <cstddef>
#include <cstdint>

// SpatialPatchMoE: x[2,64,8,128,128] f32, P=8 patches -> N=512 patches,
// router top-2 of 8 experts, per-expert {dwconv(1,7,7) -> LN(P,P) -> pw 64->128
// -> silu-gate -> pw 64->64} + residual, weighted sum of the 2 selected experts.
//
// ws layout (floats):
//   partial : [ (b*8+l)*256 + p ][64]      = 262144 floats   (patch sums per l-slice)
//   dwT     : [ e*49 + tap ][64]           = 25088 floats    (transposed dw weights)
//   sel_i   : int[2*512]                   = 1024
//   sel_w   : float[2*512]                 = 1024

#define OFF_DWT   262144
#define OFF_SELI  287232
#define OFF_SELW  288256

__device__ __forceinline__ float wave_sum64(float v) {
#pragma unroll
  for (int m = 32; m > 0; m >>= 1) v += __shfl_xor(v, m, 64);
  return v;
}

// ---------------- preprocess: transpose depthwise weights [e][c][49] -> [e][49][c]
__global__ void k_pre(const float* __restrict__ dw, float* __restrict__ dwT) {
  int idx = blockIdx.x * 256 + threadIdx.x;
  if (idx < 8 * 64 * 49) {
    int e = idx / 3136;
    int r = idx - e * 3136;
    int c = r / 49;
    int tap = r - c * 49;
    dwT[(e * 49 + tap) * 64 + c] = dw[idx];
  }
}

// ---------------- per-(b,c,l) slice: 16x16 patch sums
__global__ void k_sum(const float* __restrict__ x, float* __restrict__ partial) {
  __shared__ float psum[256];
  int t = threadIdx.x;
  int bid = blockIdx.x;
  int b = bid >> 9, c = (bid >> 3) & 63, l = bid & 7;
  psum[t] = 0.f;
  __syncthreads();
  const float4* x4 = (const float4*)(x + (((size_t)(b * 64 + c) * 8 + l) << 14));
#pragma unroll
  for (int k = 0; k < 16; ++k) {
    int f4 = k * 256 + t;               // coalesced across lanes
    float4 v = x4[f4];
    int y = f4 >> 5, xq = f4 & 31;      // 32 float4 per image row
    int p = (y >> 3) * 16 + (xq >> 1);  // patch id within 16x16
    atomicAdd(&psum[p], v.x + v.y + v.z + v.w);
  }
  __syncthreads();
  partial[((size_t)(b * 8 + l) * 256 + t) * 64 + c] = psum[t];
}

// ---------------- router: logits, top-2, softmax
__global__ void k_router(const float* __restrict__ partial,
                         const float* __restrict__ rw, const float* __restrict__ rb,
                         int* __restrict__ sel_i, float* __restrict__ sel_w) {
  int n = blockIdx.x;        // 512 patches
  int lane = threadIdx.x;    // 64 = one wave, lane = channel
  int b = n >> 8, p = n & 255;
  float s = 0.f;
#pragma unroll
  for (int l = 0; l < 8; ++l)
    s += partial[((size_t)(b * 8 + l) * 256 + p) * 64 + lane];
  float rin = s * (1.f / 512.f);
  float lg[8];
#pragma unroll
  for (int e = 0; e < 8; ++e) {
    float v = rin * rw[e * 64 + lane];
    lg[e] = wave_sum64(v) + rb[e];
  }
  // top-2, ties -> lower index (matches lax.top_k)
  int e0 = 0; float v0 = lg[0];
#pragma unroll
  for (int e = 1; e < 8; ++e) if (lg[e] > v0) { v0 = lg[e]; e0 = e; }
  int e1 = -1; float v1 = -1e30f;
#pragma unroll
  for (int e = 0; e < 8; ++e) if (e != e0 && lg[e] > v1) { v1 = lg[e]; e1 = e; }
  if (lane == 0) {
    float w1 = __expf(v1 - v0);
    float z = 1.f + w1;
    sel_i[2 * n] = e0; sel_i[2 * n + 1] = e1;
    sel_w[2 * n] = 1.f / z; sel_w[2 * n + 1] = w1 / z;
  }
}

// ---------------- depthwise conv: 2 rows per wave, fully static indexing
template <int Y0>
__device__ __forceinline__ void conv2rows(const float* __restrict__ xin,
                                          const float* __restrict__ wreg,
                                          float bias, float* __restrict__ hv) {
#pragma unroll
  for (int ry = 0; ry < 2; ++ry) {
#pragma unroll
    for (int xp = 0; xp < 8; ++xp) {
      float a = bias;
#pragma unroll
      for (int dy = 0; dy < 7; ++dy) {
        const int yy = Y0 + ry + dy - 3;      // compile-time
        if (yy >= 0 && yy <= 7) {
#pragma unroll
          for (int dx = 0; dx < 7; ++dx) {
            const int xx = xp + dx - 3;       // compile-time
            if (xx >= 0 && xx <= 7)
              a += xin[yy * 8 + xx] * wreg[dy * 7 + dx];
          }
        }
      }
      hv[ry * 8 + xp] = a;
    }
  }
}

// ---------------- main: one block per (patch n, depth l) slice [64ch x 64px]
__global__ __launch_bounds__(256) void k_main(
    const float* __restrict__ x,
    const float* __restrict__ dwT, const float* __restrict__ dwb,
    const float* __restrict__ lnw, const float* __restrict__ lnb,
    const float* __restrict__ pwin_w, const float* __restrict__ pwin_b,
    const float* __restrict__ pwout_w, const float* __restrict__ pwout_b,
    const int* __restrict__ sel_i, const float* __restrict__ sel_w,
    float* __restrict__ out) {
  __shared__ float xs[64 * 65];    // [pixel s][channel c], stride 65 (conflict-free)
  __shared__ float hbuf[64 * 65];  // [c][s] for h, then reused for gated h3
  __shared__ float red[8][64];     // LN cross-wave partials

  int t = threadIdx.x;
  int lane = t & 63;
  int wv = __builtin_amdgcn_readfirstlane(t >> 6);
  int bidx = blockIdx.x;
  int n = bidx >> 3, l = bidx & 7;
  int b = n >> 8, p = n & 255;
  int hh = p >> 4, ww = p & 15;
  // x[b][c][l][Y][X] flat: b*64*131072 + c*131072 + l*16384 + Y*128 + X
  size_t obase = (size_t)b * 64 * 131072 + (size_t)l * 16384 + (size_t)hh * 1024 + (size_t)ww * 8;

  // stage x slice into LDS (pixel-major)
  {
    int c0 = t >> 2, q = t & 3;
    const float* gp = x + obase + (size_t)c0 * 131072 + (size_t)(2 * q) * 128;
#pragma unroll
    for (int r = 0; r < 2; ++r)
#pragma unroll
      for (int hf = 0; hf < 2; ++hf) {
        const float4 v = *(const float4*)(gp + r * 128 + hf * 4);
        int s = (2 * q + r) * 8 + hf * 4;
        xs[(s + 0) * 65 + c0] = v.x;
        xs[(s + 1) * 65 + c0] = v.y;
        xs[(s + 2) * 65 + c0] = v.z;
        xs[(s + 3) * 65 + c0] = v.w;
      }
  }
  __syncthreads();

  float oacc[16];
#pragma unroll
  for (int i = 0; i < 16; ++i) oacc[i] = 0.f;

#pragma unroll 1
  for (int k = 0; k < 2; ++k) {
    int e = __builtin_amdgcn_readfirstlane(sel_i[2 * n + k]);
    float we = sel_w[2 * n + k];

    // ---- depthwise conv (lane = channel, wave = row pair) ----
    float xin[64];
#pragma unroll
    for (int j = 0; j < 64; ++j) xin[j] = xs[j * 65 + lane];
    float wreg[49];
#pragma unroll
    for (int tap = 0; tap < 49; ++tap) wreg[tap] = dwT[(e * 49 + tap) * 64 + lane];
    float bias = dwb[e * 64 + lane];
    float hv[16];
    if (wv == 0)      conv2rows<0>(xin, wreg, bias, hv);
    else if (wv == 1) conv2rows<2>(xin, wreg, bias, hv);
    else if (wv == 2) conv2rows<4>(xin, wreg, bias, hv);
    else              conv2rows<6>(xin, wreg, bias, hv);

    // ---- LayerNorm over the 64 pixels of each channel ----
    float ps = 0.f, pq = 0.f;
#pragma unroll
    for (int j = 0; j < 16; ++j) { ps += hv[j]; pq += hv[j] * hv[j]; }
    red[wv * 2 + 0][lane] = ps;
    red[wv * 2 + 1][lane] = pq;
    __syncthreads();
    float sm = red[0][lane] + red[2][lane] + red[4][lane] + red[6][lane];
    float sq = red[1][lane] + red[3][lane] + red[5][lane] + red[7][lane];
    float mu = sm * (1.f / 64.f);
    float var = sq * (1.f / 64.f) - mu * mu;
    float rstd = rsqrtf(var + 1e-5f);
#pragma unroll
    for (int j = 0; j < 16; ++j) {
      int s = (2 * wv + (j >> 3)) * 8 + (j & 7);
      float nv = (hv[j] - mu) * rstd * lnw[e * 64 + s] + lnb[e * 64 + s];
      hbuf[lane * 65 + s] = nv;   // h[c][s]
    }
    __syncthreads();

    // ---- pw_in (64 -> 128) + silu gate (lane = pixel, wave = 16 out rows) ----
    float accA[16], accG[16];
    const float* bA = pwin_b + e * 128 + wv * 16;
#pragma unroll
    for (int i = 0; i < 16; ++i) { accA[i] = bA[i]; accG[i] = bA[64 + i]; }
    const float* wA = pwin_w + ((size_t)e * 128 + wv * 16) * 64;  // uniform -> s_load
    const float* wG = wA + 64 * 64;
#pragma unroll 1
    for (int cb = 0; cb < 64; cb += 16) {
      float hc[16];
#pragma unroll
      for (int u = 0; u < 16; ++u) hc[u] = hbuf[(cb + u) * 65 + lane];
#pragma unroll
      for (int i = 0; i < 16; ++i) {
#pragma unroll
        for (int u = 0; u < 16; ++u) {
          accA[i] += wA[i * 64 + cb + u] * hc[u];
          accG[i] += wG[i * 64 + cb + u] * hc[u];
        }
      }
    }
    float h3r[16];
#pragma unroll
    for (int i = 0; i < 16; ++i) {
      float a = accA[i];
      float sg = 1.f / (1.f + __expf(-a));
      h3r[i] = a * sg * accG[i];
    }
    __syncthreads();            // all waves done reading h
#pragma unroll
    for (int i = 0; i < 16; ++i) hbuf[(wv * 16 + i) * 65 + lane] = h3r[i];
    __syncthreads();

    // ---- pw_out (64 -> 64) ----
    float accO[16];
    const float* bO = pwout_b + e * 64 + wv * 16;
#pragma unroll
    for (int i = 0; i < 16; ++i) accO[i] = bO[i];
    const float* wO = pwout_w + ((size_t)e * 64 + wv * 16) * 64;
#pragma unroll 1
    for (int cb = 0; cb < 64; cb += 16) {
      float hc[16];
#pragma unroll
      for (int u = 0; u < 16; ++u) hc[u] = hbuf[(cb + u) * 65 + lane];
#pragma unroll
      for (int i = 0; i < 16; ++i)
#pragma unroll
        for (int u = 0; u < 16; ++u)
          accO[i] += wO[i * 64 + cb + u] * hc[u];
    }
#pragma unroll
    for (int i = 0; i < 16; ++i) oacc[i] += we * accO[i];
    __syncthreads();            // before next expert overwrites hbuf
  }

  // ---- residual + store (lane = pixel, wave*16+i = channel) ----
  int py = lane >> 3, px = lane & 7;
#pragma unroll
  for (int i = 0; i < 16; ++i) {
    int c_out = wv * 16 + i;
    float v = xs[lane * 65 + c_out] + oacc[i];
    out[obase + (size_t)c_out * 131072 + (size_t)py * 128 + px] = v;
  }
}

extern "C" void kernel_launch(void* const* d_in, const int* in_sizes, int n_in,
                              void* d_out, int out_size, void* d_ws, size_t ws_size,
                              hipStream_t stream) {
  const float* x       = (const float*)d_in[0];
  const float* rw      = (const float*)d_in[1];
  const float* rb      = (const float*)d_in[2];
  const float* dww     = (const float*)d_in[3];
  const float* dwb     = (const float*)d_in[4];
  const float* lnw     = (const float*)d_in[5];
  const float* lnb     = (const float*)d_in[6];
  const float* pwin_w  = (const float*)d_in[7];
  const float* pwin_b  = (const float*)d_in[8];
  const float* pwout_w = (const float*)d_in[9];
  const float* pwout_b = (const float*)d_in[10];
  float* out = (float*)d_out;

  float* wsf     = (float*)d_ws;
  float* partial = wsf;
  float* dwT     = wsf + OFF_DWT;
  int*   sel_i   = (int*)(wsf + OFF_SELI);
  float* sel_w   = wsf + OFF_SELW;

  hipLaunchKernelGGL(k_pre,    dim3(98),   dim3(256), 0, stream, dww, dwT);
  hipLaunchKernelGGL(k_sum,    dim3(1024), dim3(256), 0, stream, x, partial);
  hipLaunchKernelGGL(k_router, dim3(512),  dim3(64),  0, stream, partial, rw, rb, sel_i, sel_w);
  hipLaunchKernelGGL(k_main,   dim3(4096), dim3(256), 0, stream, x, dwT, dwb, lnw, lnb,
                     pwin_w, pwin_b, pwout_w, pwout_b, sel_i, sel_w, out);
}

// Round 2
// 225.781 us; speedup vs baseline: 2.9826x; 2.9826x over previous
//
#include <hip/hip_runtime.h>
#include <cstddef>
#include <cstdint>

// SpatialPatchMoE on MI355X.
// x[2,64,8,128,128] f32, P=8 -> N=512 patches; router top-2/8 experts;
// per expert: dwconv(1,7,7) -> LN(8,8) -> pw 64->128 -> silu*gate -> pw 64->64;
// out = x + sum_k w_k * expert_k.  Pointwise matmuls in bf16 MFMA 16x16x32.
//
// ws layout (bytes):
//   partial4 : [b][lp][p][c] f32  (2*4*256*64)        @ 0        (524288 B)
//   dwT      : [e][tap][c] f32    (8*49*64)           @ 524288   (100352 B)
//   sel_i    : int[2*512]                              @ 624640   (4096 B)
//   sel_w    : f32[2*512]                              @ 628736   (4096 B)
//   wInBf    : bf16 [e][128][64]                       @ 632832   (131072 B)
//   wOutBf   : bf16 [e][64][64]                        @ 763904   (65536 B)
//   total 829440 B

typedef __attribute__((ext_vector_type(8))) short short8;
typedef __attribute__((ext_vector_type(4))) float f32x4;

#define XS_STRIDE 68   // floats per channel row of xs  (272 B, 16B aligned)
#define H_STRIDE  72   // bf16 per pixel row of h/h3    (144 B, 16B aligned)

__device__ __forceinline__ unsigned short f2bf(float f) {
  unsigned u = __builtin_bit_cast(unsigned, f);
  unsigned r = (u + 0x7FFFu + ((u >> 16) & 1u)) >> 16;
  return (unsigned short)r;
}

__device__ __forceinline__ float wave_sum64(float v) {
#pragma unroll
  for (int m = 32; m > 0; m >>= 1) v += __shfl_xor(v, m, 64);
  return v;
}

// ---------------- preprocess: dw transpose + pw weights -> bf16
__global__ void k_pre(const float* __restrict__ dw,
                      const float* __restrict__ pwin,
                      const float* __restrict__ pwout,
                      float* __restrict__ dwT,
                      unsigned short* __restrict__ wIn,
                      unsigned short* __restrict__ wOut) {
  int idx = blockIdx.x * 256 + threadIdx.x;
  if (idx < 25088) {
    int e = idx / 3136;
    int r = idx - e * 3136;
    int c = r / 49;
    int tap = r - c * 49;
    dwT[(e * 49 + tap) * 64 + c] = dw[idx];
  } else if (idx < 25088 + 65536) {
    int i = idx - 25088;
    wIn[i] = f2bf(pwin[i]);
  } else if (idx < 25088 + 65536 + 32768) {
    int i = idx - 90624;
    wOut[i] = f2bf(pwout[i]);
  }
}

// ---------------- patch sums, deterministic: block per (b, c, l-pair)
__global__ __launch_bounds__(256) void k_sum(const float* __restrict__ x,
                                             float* __restrict__ partial4) {
  __shared__ float red[256 * 17];
  int t = threadIdx.x, bid = blockIdx.x;
  int b = bid >> 8, c = (bid >> 2) & 63, lp = bid & 3;
  float acc[16];
#pragma unroll
  for (int k = 0; k < 16; ++k) acc[k] = 0.f;
  const float4* x4 = (const float4*)x + ((size_t)((b * 64 + c) * 8) + lp * 2) * 4096;
#pragma unroll
  for (int l2 = 0; l2 < 2; ++l2)
#pragma unroll
    for (int k = 0; k < 16; ++k) {
      float4 v = x4[l2 * 4096 + k * 256 + t];
      acc[k] += v.x + v.y + v.z + v.w;   // patch row within slice == k
    }
  int pcol = (t & 31) >> 1;
  int slot = ((t & 1) << 3) | (t >> 5);
#pragma unroll
  for (int k = 0; k < 16; ++k) red[(k * 16 + pcol) * 17 + slot] = acc[k];
  __syncthreads();
  float s = 0.f;
#pragma unroll
  for (int j = 0; j < 16; ++j) s += red[t * 17 + j];
  partial4[((size_t)(b * 4 + lp) * 256 + t) * 64 + c] = s;
}

// ---------------- router: logits, top-2, softmax (1 wave per patch)
__global__ void k_router(const float* __restrict__ partial4,
                         const float* __restrict__ rw, const float* __restrict__ rb,
                         int* __restrict__ sel_i, float* __restrict__ sel_w) {
  int n = blockIdx.x;
  int lane = threadIdx.x;
  int b = n >> 8, p = n & 255;
  float s = 0.f;
#pragma unroll
  for (int lp = 0; lp < 4; ++lp)
    s += partial4[((size_t)(b * 4 + lp) * 256 + p) * 64 + lane];
  float rin = s * (1.f / 512.f);
  float lg[8];
#pragma unroll
  for (int e = 0; e < 8; ++e) {
    float v = rin * rw[e * 64 + lane];
    lg[e] = wave_sum64(v) + rb[e];
  }
  int e0 = 0; float v0 = lg[0];
#pragma unroll
  for (int e = 1; e < 8; ++e) if (lg[e] > v0) { v0 = lg[e]; e0 = e; }
  int e1 = -1; float v1 = -1e30f;
#pragma unroll
  for (int e = 0; e < 8; ++e) if (e != e0 && lg[e] > v1) { v1 = lg[e]; e1 = e; }
  if (lane == 0) {
    float w1 = __expf(v1 - v0);
    float z = 1.f + w1;
    sel_i[2 * n] = e0; sel_i[2 * n + 1] = e1;
    sel_w[2 * n] = 1.f / z; sel_w[2 * n + 1] = w1 / z;
  }
}

// ---------------- depthwise conv, row-streaming, static indexing
template <int Y0>
__device__ __forceinline__ void convRows(const float* __restrict__ xsLane,
                                         const float* __restrict__ wreg,
                                         float* __restrict__ hv) {
  constexpr int RLO = (Y0 - 3 < 0) ? 0 : Y0 - 3;
  constexpr int RHI = (Y0 + 4 > 7) ? 7 : Y0 + 4;
#pragma unroll
  for (int r = RLO; r <= RHI; ++r) {
    const float4 ra = *(const float4*)(xsLane + r * 8);
    const float4 rb = *(const float4*)(xsLane + r * 8 + 4);
    const float row[8] = {ra.x, ra.y, ra.z, ra.w, rb.x, rb.y, rb.z, rb.w};
#pragma unroll
    for (int ry = 0; ry < 2; ++ry) {
      const int dy = r - (Y0 + ry) + 3;
      if (dy >= 0 && dy <= 6) {
#pragma unroll
        for (int xp = 0; xp < 8; ++xp)
#pragma unroll
          for (int dx = 0; dx < 7; ++dx) {
            const int xx = xp + dx - 3;
            if (xx >= 0 && xx < 8) hv[ry * 8 + xp] += row[xx] * wreg[dy * 7 + dx];
          }
      }
    }
  }
}

// ---------------- main: one block per (patch n, depth l); 4 waves
__global__ __launch_bounds__(256, 4) void k_main(
    const float* __restrict__ x,
    const float* __restrict__ dwT, const float* __restrict__ dwb,
    const float* __restrict__ lnw, const float* __restrict__ lnb,
    const float* __restrict__ pwin_b, const float* __restrict__ pwout_b,
    const unsigned short* __restrict__ wInBf,
    const unsigned short* __restrict__ wOutBf,
    const int* __restrict__ sel_i, const float* __restrict__ sel_w,
    float* __restrict__ out) {
  __shared__ __align__(16) float xs[64 * XS_STRIDE];          // [c][s] f32
  __shared__ __align__(16) unsigned short hbf[64 * H_STRIDE]; // [px][c] bf16
  __shared__ __align__(16) unsigned short h3bf[64 * H_STRIDE];
  __shared__ float lnred[8][64];

  const int t = threadIdx.x;
  const int lane = t & 63;
  const int wv = __builtin_amdgcn_readfirstlane(t >> 6);
  const int r15 = lane & 15, r4 = lane >> 4;

  const int bidx = blockIdx.x;
  const int n = bidx >> 3, l = bidx & 7;
  const int b = n >> 8, p = n & 255;
  const int hh = p >> 4, ww = p & 15;
  const size_t obase = (size_t)b * 8388608 + (size_t)l * 16384 +
                       (size_t)hh * 1024 + (size_t)ww * 8;

  // ---- stage x slice into LDS: [c][s], one float4 per (thread, iter)
#pragma unroll
  for (int i = 0; i < 4; ++i) {
    int g = i * 256 + t;
    int hf = g & 1, y = (g >> 1) & 7, c = g >> 4;
    float4 v = *(const float4*)(x + obase + (size_t)c * 131072 + y * 128 + hf * 4);
    *(float4*)(xs + c * XS_STRIDE + y * 8 + hf * 4) = v;
  }
  __syncthreads();

  float oacc[16];
#pragma unroll
  for (int i = 0; i < 16; ++i) oacc[i] = 0.f;

#pragma unroll 1
  for (int k = 0; k < 2; ++k) {
    const int e = __builtin_amdgcn_readfirstlane(sel_i[2 * n + k]);
    const float we = sel_w[2 * n + k];

    // ---- depthwise conv: lane = channel, wave wv owns rows 2wv..2wv+1
    float wreg[49];
#pragma unroll
    for (int tap = 0; tap < 49; ++tap) wreg[tap] = dwT[(e * 49 + tap) * 64 + lane];
    float hv[16];
    {
      const float bias = dwb[e * 64 + lane];
#pragma unroll
      for (int j = 0; j < 16; ++j) hv[j] = bias;
    }
    const float* xsLane = xs + lane * XS_STRIDE;
    if (wv == 0)      convRows<0>(xsLane, wreg, hv);
    else if (wv == 1) convRows<2>(xsLane, wreg, hv);
    else if (wv == 2) convRows<4>(xsLane, wreg, hv);
    else              convRows<6>(xsLane, wreg, hv);

    // ---- LayerNorm over 64 pixels per channel
    float ps = 0.f, pq = 0.f;
#pragma unroll
    for (int j = 0; j < 16; ++j) { ps += hv[j]; pq += hv[j] * hv[j]; }
    lnred[wv * 2 + 0][lane] = ps;
    lnred[wv * 2 + 1][lane] = pq;
    __syncthreads();  // sync1
    float sm = lnred[0][lane] + lnred[2][lane] + lnred[4][lane] + lnred[6][lane];
    float sq = lnred[1][lane] + lnred[3][lane] + lnred[5][lane] + lnred[7][lane];
    float mu = sm * (1.f / 64.f);
    float var = sq * (1.f / 64.f) - mu * mu;
    float rstd = rsqrtf(var + 1e-5f);
#pragma unroll
    for (int j = 0; j < 16; ++j) {
      int s = 16 * wv + j;   // pixel index
      float nv = (hv[j] - mu) * rstd * lnw[e * 64 + s] + lnb[e * 64 + s];
      hbf[s * H_STRIDE + lane] = f2bf(nv);   // h[px][c] bf16
    }
    __syncthreads();  // sync2: h ready

    // ---- pw_in (64->128) via MFMA; wave wv owns A-rows [16wv,16wv+16) and G-rows +64
    const unsigned short* wInE = wInBf + (size_t)e * 8192;
    short8 aA[2], aG[2];
#pragma unroll
    for (int kf = 0; kf < 2; ++kf) {
      aA[kf] = *(const short8*)(wInE + (16 * wv + r15) * 64 + kf * 32 + r4 * 8);
      aG[kf] = *(const short8*)(wInE + (64 + 16 * wv + r15) * 64 + kf * 32 + r4 * 8);
    }
    f32x4 accA[4], accG[4];
#pragma unroll
    for (int nt = 0; nt < 4; ++nt)
#pragma unroll
      for (int v = 0; v < 4; ++v) {
        accA[nt][v] = pwin_b[e * 128 + 16 * wv + r4 * 4 + v];
        accG[nt][v] = pwin_b[e * 128 + 64 + 16 * wv + r4 * 4 + v];
      }
#pragma unroll
    for (int nt = 0; nt < 4; ++nt)
#pragma unroll
      for (int kf = 0; kf < 2; ++kf) {
        short8 bfr = *(const short8*)(hbf + (16 * nt + r15) * H_STRIDE + kf * 32 + r4 * 8);
        accA[nt] = __builtin_amdgcn_mfma_f32_16x16x32_bf16(aA[kf], bfr, accA[nt], 0, 0, 0);
        accG[nt] = __builtin_amdgcn_mfma_f32_16x16x32_bf16(aG[kf], bfr, accG[nt], 0, 0, 0);
      }
    // silu(a) * g -> h3 (bf16, [px][c])
#pragma unroll
    for (int nt = 0; nt < 4; ++nt)
#pragma unroll
      for (int v = 0; v < 4; ++v) {
        float a = accA[nt][v];
        float g = accG[nt][v];
        float hval = (a / (1.f + __expf(-a))) * g;
        h3bf[(16 * nt + r15) * H_STRIDE + 16 * wv + r4 * 4 + v] = f2bf(hval);
      }
    __syncthreads();  // sync3: h3 ready

    // ---- pw_out (64->64) via MFMA; wave wv owns rows [16wv,16wv+16)
    const unsigned short* wOutE = wOutBf + (size_t)e * 4096;
    short8 aO[2];
#pragma unroll
    for (int kf = 0; kf < 2; ++kf)
      aO[kf] = *(const short8*)(wOutE + (16 * wv + r15) * 64 + kf * 32 + r4 * 8);
    f32x4 accO[4];
#pragma unroll
    for (int nt = 0; nt < 4; ++nt)
#pragma unroll
      for (int v = 0; v < 4; ++v) accO[nt][v] = 0.f;
#pragma unroll
    for (int nt = 0; nt < 4; ++nt)
#pragma unroll
      for (int kf = 0; kf < 2; ++kf) {
        short8 bfr = *(const short8*)(h3bf + (16 * nt + r15) * H_STRIDE + kf * 32 + r4 * 8);
        accO[nt] = __builtin_amdgcn_mfma_f32_16x16x32_bf16(aO[kf], bfr, accO[nt], 0, 0, 0);
      }
    float bO[4];
#pragma unroll
    for (int v = 0; v < 4; ++v) bO[v] = pwout_b[e * 64 + 16 * wv + r4 * 4 + v];
#pragma unroll
    for (int nt = 0; nt < 4; ++nt)
#pragma unroll
      for (int v = 0; v < 4; ++v) oacc[nt * 4 + v] += we * (accO[nt][v] + bO[v]);
    // no barrier here: sync1 of next iteration protects hbf/h3bf reuse
  }

  // ---- residual + store: c = 16wv + 4*r4 + v, px = 16nt + r15
#pragma unroll
  for (int nt = 0; nt < 4; ++nt)
#pragma unroll
    for (int v = 0; v < 4; ++v) {
      int c = 16 * wv + 4 * r4 + v;
      int px = 16 * nt + r15;
      float val = xs[c * XS_STRIDE + px] + oacc[nt * 4 + v];
      out[obase + (size_t)c * 131072 + (px >> 3) * 128 + (px & 7)] = val;
    }
}

extern "C" void kernel_launch(void* const* d_in, const int* in_sizes, int n_in,
                              void* d_out, int out_size, void* d_ws, size_t ws_size,
                              hipStream_t stream) {
  const float* x       = (const float*)d_in[0];
  const float* rw      = (const float*)d_in[1];
  const float* rb      = (const float*)d_in[2];
  const float* dww     = (const float*)d_in[3];
  const float* dwb     = (const float*)d_in[4];
  const float* lnw     = (const float*)d_in[5];
  const float* lnb     = (const float*)d_in[6];
  const float* pwin_w  = (const float*)d_in[7];
  const float* pwin_b  = (const float*)d_in[8];
  const float* pwout_w = (const float*)d_in[9];
  const float* pwout_b = (const float*)d_in[10];
  float* out = (float*)d_out;

  char* ws = (char*)d_ws;
  float*          partial4 = (float*)ws;
  float*          dwT      = (float*)(ws + 524288);
  int*            sel_i    = (int*)(ws + 624640);
  float*          sel_w    = (float*)(ws + 628736);
  unsigned short* wInBf    = (unsigned short*)(ws + 632832);
  unsigned short* wOutBf   = (unsigned short*)(ws + 763904);

  hipLaunchKernelGGL(k_pre,    dim3(482),  dim3(256), 0, stream,
                     dww, pwin_w, pwout_w, dwT, wInBf, wOutBf);
  hipLaunchKernelGGL(k_sum,    dim3(512),  dim3(256), 0, stream, x, partial4);
  hipLaunchKernelGGL(k_router, dim3(512),  dim3(64),  0, stream,
                     partial4, rw, rb, sel_i, sel_w);
  hipLaunchKernelGGL(k_main,   dim3(4096), dim3(256), 0, stream,
                     x, dwT, dwb, lnw, lnb, pwin_b, pwout_b,
                     wInBf, wOutBf, sel_i, sel_w, out);
}